// Round 15
// baseline (185.221 us; speedup 1.0000x reference)
//
#include <hip/hip_runtime.h>

typedef __attribute__((ext_vector_type(8))) short short8;
typedef __attribute__((ext_vector_type(4))) float f32x4;
typedef __attribute__((ext_vector_type(16))) float f32x16;
typedef __attribute__((ext_vector_type(4))) unsigned int u32x4;
typedef __attribute__((ext_vector_type(4))) unsigned short u16x4;
typedef unsigned int u32;
typedef unsigned short u16;

#define DEV static __device__ __forceinline__

DEV u16 f2bf(float f) {
  union { float f; u32 u; } c; c.f = f;
  u32 r = (c.u + 0x7fffu + ((c.u >> 16) & 1u)) >> 16;
  return (u16)r;
}
DEV float bf2f(u16 v) {
  union { u32 u; float f; } c; c.u = ((u32)v) << 16;
  return c.f;
}
DEV short8 pack8(float4 a, float4 b) {
  short8 r;
  r[0]=(short)f2bf(a.x); r[1]=(short)f2bf(a.y); r[2]=(short)f2bf(a.z); r[3]=(short)f2bf(a.w);
  r[4]=(short)f2bf(b.x); r[5]=(short)f2bf(b.y); r[6]=(short)f2bf(b.z); r[7]=(short)f2bf(b.w);
  return r;
}
DEV u32 cvtpk(float lo, float hi) {  // packed bf16 pair, RTNE
  u32 r;
  asm("v_cvt_pk_bf16_f32 %0, %1, %2" : "=v"(r) : "v"(lo), "v"(hi));
  return r;
}

// fast exp2: single v_exp_f32 (library exp2f carries range-check overhead)
#if __has_builtin(__builtin_amdgcn_exp2f)
DEV float fexp2(float x) { return __builtin_amdgcn_exp2f(x); }
#else
DEV float fexp2(float x) { return exp2f(x); }
#endif

DEV void glds16(const void* g, void* l) {
  __builtin_amdgcn_global_load_lds((const __attribute__((address_space(1))) u32*)g,
                                   (__attribute__((address_space(3))) u32*)l, 16, 0, 0);
}

DEV f32x16 mfma32(short8 a, short8 b, f32x16 c) {
  return __builtin_amdgcn_mfma_f32_32x32x16_bf16(a, b, c, 0, 0, 0);
}

constexpr int CDIM = 1024, TT = 2048, NH = 16, DK = 64;
// Q pre-scale: 1/sqrt(64) * log2(e)  (softmax runs in exp2 domain)
#define QSC 0.1803368801111601f

// ---------------- fp32 -> bf16 conversion for X, W_qkv, W_out --------------
__global__ void conv_bf16(const float* __restrict__ X, const float* __restrict__ W1,
                          const float* __restrict__ W2, u16* __restrict__ Xb,
                          u16* __restrict__ W1b, u16* __restrict__ W2b) {
  const long n0 = 1048576, n1 = 393216, n2 = 131072;  // 8-elem groups
  for (long i = (long)blockIdx.x * blockDim.x + threadIdx.x; i < n0 + n1 + n2;
       i += (long)gridDim.x * blockDim.x) {
    const float* s; u16* d; long j = i;
    if (j < n0) { s = X; d = Xb; }
    else if (j < n0 + n1) { j -= n0; s = W1; d = W1b; }
    else { j -= n0 + n1; s = W2; d = W2b; }
    float4 a = ((const float4*)s)[2 * j];
    float4 b = ((const float4*)s)[2 * j + 1];
    ((short8*)d)[j] = pack8(a, b);
  }
}

// ---------------- QKV GEMM v5 (r13 best, 72.7us): 256x128 tile, 8 waves ----
__global__ void __launch_bounds__(512, 2)
qkv_gemm5(const u16* __restrict__ A, const u16* __restrict__ B,
          const float* __restrict__ bias, u16* __restrict__ Qb,
          u16* __restrict__ Kb, u16* __restrict__ VTb) {
  __shared__ u16 LS[3][3][128][64];  // [buf][chunk: A-lo, A-hi, B][row][col]
  const int tid = threadIdx.x, lane = tid & 63, wid = tid >> 6;
  const int lo = lane & 15, lg = lane >> 4;
  const int wm = wid >> 1, wn = wid & 1;          // wave tile: 64 rows x 64 cols
  const int rin = lane >> 3, blk = lane & 7;
  const int m0 = blockIdx.x * 256, n0 = blockIdx.y * 128;
  const int r7 = lo & 7;

  const u16* gA = A + (size_t)(m0 + wid * 16 + rin) * CDIM + (blk ^ rin) * 8;
  const u16* gB = B + (size_t)(n0 + wid * 16 + rin) * CDIM + (blk ^ rin) * 8;
  u16* lsb = &LS[0][0][wid * 16][0];

#define STGH0(bufi, kt)                                          \
  {                                                              \
    const int k0e = (kt) * 64;                                   \
    u16* lb = lsb + (bufi) * 24576;                              \
    glds16(gA + k0e, lb);                                        \
    glds16(gA + k0e + 8 * CDIM, lb + 512);                       \
    glds16(gB + k0e, lb + 16384);                                \
  }
#define STGH1(bufi, kt)                                          \
  {                                                              \
    const int k0e = (kt) * 64;                                   \
    u16* lb = lsb + (bufi) * 24576;                              \
    glds16(gA + k0e + 128 * CDIM, lb + 8192);                    \
    glds16(gA + k0e + 136 * CDIM, lb + 8704);                    \
    glds16(gB + k0e + 8 * CDIM, lb + 16896);                     \
  }

  f32x4 acc[4][4];
  const f32x4 fz = {0.f, 0.f, 0.f, 0.f};
#pragma unroll
  for (int i = 0; i < 4; ++i)
#pragma unroll
    for (int j = 0; j < 4; ++j) acc[i][j] = fz;

  STGH0(0, 0); STGH1(0, 0);
  STGH0(1, 1); STGH1(1, 1);
  asm volatile("s_waitcnt vmcnt(6)" ::: "memory");
  __builtin_amdgcn_s_barrier();

  int b0 = 0, b1 = 1, b2 = 2;
  for (int T = 0; T < 16; ++T) {
    const u16* pA = &LS[b0][wm >> 1][(wm & 1) * 64][0];
    const u16* pB = &LS[b0][2][wn * 64][0];
    short8 af[4], bfr[4];
    // ================= phase 0 (kk = 0) =================
#pragma unroll
    for (int mi = 0; mi < 4; ++mi)
      af[mi] = *(const short8*)&pA[(mi * 16 + lo) * 64 + ((lg ^ r7) * 8)];
#pragma unroll
    for (int ni = 0; ni < 4; ++ni)
      bfr[ni] = *(const short8*)&pB[(ni * 16 + lo) * 64 + ((lg ^ r7) * 8)];
    if (T < 14) STGH0(b2, T + 2);
    __builtin_amdgcn_sched_barrier(0);
    __builtin_amdgcn_s_barrier();
    asm volatile("s_waitcnt lgkmcnt(0)" ::: "memory");
    __builtin_amdgcn_sched_barrier(0);
    __builtin_amdgcn_s_setprio(1);
#pragma unroll
    for (int mi = 0; mi < 4; ++mi)
#pragma unroll
      for (int ni = 0; ni < 4; ++ni)
        acc[mi][ni] = __builtin_amdgcn_mfma_f32_16x16x32_bf16(af[mi], bfr[ni], acc[mi][ni], 0, 0, 0);
    __builtin_amdgcn_s_setprio(0);
    __builtin_amdgcn_sched_barrier(0);
    __builtin_amdgcn_s_barrier();
    // ================= phase 1 (kk = 1) =================
#pragma unroll
    for (int mi = 0; mi < 4; ++mi)
      af[mi] = *(const short8*)&pA[(mi * 16 + lo) * 64 + (((4 + lg) ^ r7) * 8)];
#pragma unroll
    for (int ni = 0; ni < 4; ++ni)
      bfr[ni] = *(const short8*)&pB[(ni * 16 + lo) * 64 + (((4 + lg) ^ r7) * 8)];
    if (T < 14) STGH1(b2, T + 2);
    __builtin_amdgcn_sched_barrier(0);
    if (T < 14) {
      asm volatile("s_waitcnt vmcnt(6)" ::: "memory");   // gate tile T+1
    } else if (T == 14) {
      asm volatile("s_waitcnt vmcnt(0)" ::: "memory");   // gate tile 15
    }
    __builtin_amdgcn_s_barrier();
    asm volatile("s_waitcnt lgkmcnt(0)" ::: "memory");
    __builtin_amdgcn_sched_barrier(0);
    __builtin_amdgcn_s_setprio(1);
#pragma unroll
    for (int mi = 0; mi < 4; ++mi)
#pragma unroll
      for (int ni = 0; ni < 4; ++ni)
        acc[mi][ni] = __builtin_amdgcn_mfma_f32_16x16x32_bf16(af[mi], bfr[ni], acc[mi][ni], 0, 0, 0);
    __builtin_amdgcn_s_setprio(0);
    __builtin_amdgcn_sched_barrier(0);
    __builtin_amdgcn_s_barrier();
    const int tmp = b0; b0 = b1; b1 = b2; b2 = tmp;
  }
#undef STGH0
#undef STGH1

  // ---- scatter epilogue ----
#pragma unroll
  for (int ni = 0; ni < 4; ++ni) {
    const int o = n0 + wn * 64 + ni * 16 + lo;
    const float bv = bias[o];
    const int hh = o / 192, rem = o - hh * 192, which = rem >> 6, d = rem & 63;
#pragma unroll
    for (int mi = 0; mi < 4; ++mi) {
      const int mb = m0 + wm * 64 + mi * 16 + lg * 4;
      const int bbi = mb >> 11, t0 = mb & 2047;
      const int bh = bbi * NH + hh;
      if (which == 2) {
        u16x4 pk;
#pragma unroll
        for (int r = 0; r < 4; ++r) pk[r] = f2bf(acc[mi][ni][r] + bv);
        *(u16x4*)&VTb[((size_t)bh * DK + d) * TT + t0] = pk;
      } else if (which == 1) {
#pragma unroll
        for (int r = 0; r < 4; ++r)
          Kb[((size_t)bh * TT + t0 + r) * DK + d] = f2bf(acc[mi][ni][r] + bv);
      } else {
#pragma unroll
        for (int r = 0; r < 4; ++r)
          Qb[((size_t)bh * TT + t0 + r) * DK + d] = f2bf((acc[mi][ni][r] + bv) * QSC);
      }
    }
  }
}

// ---------------- Flash attention v10: no-max softmax, 4 blocks/CU ----------
__global__ void __launch_bounds__(256, 4)
attn10(const u16* __restrict__ Qb, const u16* __restrict__ Kb,
       const u16* __restrict__ VTb, u16* __restrict__ PA, u16* __restrict__ PB,
       float* __restrict__ ML) {
  __shared__ u16 Kls[2][64][64];
  __shared__ u16 Vls[2][64][64];
  const int tid = threadIdx.x, lane = tid & 63, wv = tid >> 6;
  const int lq = lane & 31, h = lane >> 5;
  const int id = blockIdx.x;
  const int w = (id & 7) * 128 + (id >> 3);  // logical work index, XCD-chunked
  const int bh = w >> 4;                     // 8 bh per XCD
  const int pj = w & 7;                      // pair index
  const int sp = (w >> 3) & 1;               // kv parity
  const int bb = bh >> 4, head = bh & 15;
  const u16* Qp = Qb + (size_t)bh * TT * DK;
  const u16* Kp = Kb + (size_t)bh * TT * DK;
  const u16* Vp = VTb + (size_t)bh * DK * TT;
  const int rin = lane >> 3, blk = lane & 7;
  u16* PO = sp ? PB : PA;

  const u16* kga = Kp + (size_t)(wv * 16 + rin) * DK + (blk ^ rin) * 8;
  const u16* vga = Vp + (size_t)(wv * 16 + rin) * TT + (blk ^ rin) * 8;
  u16* kls0 = &Kls[0][wv * 16][0];
  u16* vls0 = &Vls[0][wv * 16][0];
  const int lds_half = 64 * 64;  // u16 elems between buf 0 and 1

#define STAGE10(bufi, kvt_)                                                 \
  {                                                                         \
    const int o_ = (bufi) * lds_half;                                       \
    glds16(kga + (size_t)(kvt_) * 4096, kls0 + o_);                         \
    glds16(kga + (size_t)(kvt_) * 4096 + 512, kls0 + o_ + 512);             \
    glds16(vga + (size_t)(kvt_) * 64, vls0 + o_);                           \
    glds16(vga + (size_t)(kvt_) * 64 + 8 * TT, vls0 + o_ + 512);            \
  }

  for (int pi = 0; pi < 2; ++pi) {
    const int qtile = pi ? (15 - pj) : pj;
    const int q0w = qtile * 128 + wv * 32;
    const int qrow = q0w + lq;

    short8 qw[4];
#pragma unroll
    for (int kk = 0; kk < 4; ++kk)
      qw[kk] = *(const short8*)&Qp[(size_t)qrow * DK + kk * 16 + h * 8];

    f32x16 oa0, oa1;
#pragma unroll
    for (int r = 0; r < 16; ++r) { oa0[r] = 0.f; oa1[r] = 0.f; }
    float l_s = 0.f;

    const int nt = 2 * qtile + 2;
    STAGE10(0, sp);
    __syncthreads();
    int buf = 0;
    for (int kvt = sp; kvt < nt; kvt += 2) {
      const int kv0 = kvt * 64;
      if (kvt + 2 < nt) STAGE10(buf ^ 1, kvt + 2);
      if (kv0 <= q0w + 31) {
        f32x16 s0, s1;
#pragma unroll
        for (int r = 0; r < 16; ++r) { s0[r] = 0.f; s1[r] = 0.f; }
        __builtin_amdgcn_s_setprio(1);
#pragma unroll
        for (int kk = 0; kk < 4; ++kk) {
          const short8 kf0 = *(const short8*)&Kls[buf][lq][(((2 * kk + h) ^ (lq & 7)) * 8)];
          const short8 kf1 = *(const short8*)&Kls[buf][32 + lq][(((2 * kk + h) ^ (lq & 7)) * 8)];
          s0 = mfma32(kf0, qw[kk], s0);
          s1 = mfma32(kf1, qw[kk], s1);
        }
        __builtin_amdgcn_s_setprio(0);
        const bool diag = (kv0 + 63 > q0w);
        if (diag) {
          const int lim = qrow - kv0 - 4 * h;
#pragma unroll
          for (int r = 0; r < 16; ++r) {
            const int kl = (r & 3) + 8 * (r >> 2);
            s0[r] = (kl <= lim) ? s0[r] : -1e30f;
            s1[r] = (kl + 32 <= lim) ? s1[r] : -1e30f;
          }
        }
        float rsa = 0.f, rsb = 0.f, rsc = 0.f, rsd = 0.f;
#pragma unroll
        for (int r = 0; r < 16; r += 4) {
          const float a0 = fexp2(s0[r]),     a1 = fexp2(s1[r]);
          const float b0 = fexp2(s0[r + 1]), b1 = fexp2(s1[r + 1]);
          const float c0 = fexp2(s0[r + 2]), c1 = fexp2(s1[r + 2]);
          const float d0 = fexp2(s0[r + 3]), d1 = fexp2(s1[r + 3]);
          s0[r] = a0; s1[r] = a1; s0[r + 1] = b0; s1[r + 1] = b1;
          s0[r + 2] = c0; s1[r + 2] = c1; s0[r + 3] = d0; s1[r + 3] = d1;
          rsa += a0 + a1; rsb += b0 + b1; rsc += c0 + c1; rsd += d0 + d1;
        }
        float rs = (rsa + rsb) + (rsc + rsd);
        rs += __shfl_xor(rs, 32);
        l_s += rs;
#pragma unroll
        for (int s = 0; s < 2; ++s) {
          u32 C[8];
#pragma unroll
          for (int j = 0; j < 8; ++j)
            C[j] = s ? cvtpk(s1[2 * j], s1[2 * j + 1]) : cvtpk(s0[2 * j], s0[2 * j + 1]);
#pragma unroll
          for (int b = 0; b < 2; ++b) {
            const int o = 4 * b;
            const u32 D1 = h ? C[o + 0] : C[o + 2];
            const u32 D2 = h ? C[o + 1] : C[o + 3];
            const u32 R1 = __shfl_xor(D1, 32);
            const u32 R2 = __shfl_xor(D2, 32);
            union { u32x4 w; short8 s8; } pa;
            pa.w[0] = h ? R1 : C[o + 0];
            pa.w[1] = h ? R2 : C[o + 1];
            pa.w[2] = h ? C[o + 2] : R1;
            pa.w[3] = h ? C[o + 3] : R2;
            const int ks = 2 * s + b;
            const short8 vb0 = *(const short8*)&Vls[buf][lq][(((2 * ks + h) ^ (lq & 7)) * 8)];
            const short8 vb1 = *(const short8*)&Vls[buf][32 + lq][(((2 * ks + h) ^ (lq & 7)) * 8)];
            __builtin_amdgcn_s_setprio(1);
            oa0 = mfma32(pa.s8, vb0, oa0);
            oa1 = mfma32(pa.s8, vb1, oa1);
            __builtin_amdgcn_s_setprio(0);
          }
        }
      }
      __syncthreads();
      buf ^= 1;
    }

#pragma unroll
    for (int r = 0; r < 16; ++r) {
      const int t = q0w + (r & 3) + 8 * (r >> 2) + 4 * h;
      const size_t rowb = ((size_t)(bb * TT + t)) * CDIM + head * DK;
      PO[rowb + lq] = f2bf(oa0[r]);
      PO[rowb + 32 + lq] = f2bf(oa1[r]);
    }
    if (h == 0) ML[((size_t)(sp * 64 + bh) << 11) + qrow] = l_s;
    __syncthreads();
  }
#undef STAGE10
}

// ---------------- Output GEMM v3: fused merge epilogue in A-staging --------
// A = (PA + PB) * il(row, head), head == k-tile index (CDIM = NH*DK).
// A reg-staged with XOR-8 swizzled ds_write; B gl_lds with pre-swizzled src.
__global__ void out_gemm3(const u16* __restrict__ PA, const u16* __restrict__ PB,
                          const float* __restrict__ ML, const u16* __restrict__ B,
                          const float* __restrict__ bias, float* __restrict__ Out) {
  __shared__ u16 As[128][64];
  __shared__ u16 Bs[128][64];
  const int tid = threadIdx.x, lane = tid & 63, wv = tid >> 6;
  const int wr = wv >> 1, wc = wv & 1, lo = lane & 15, lg = lane >> 4;
  const int m0 = blockIdx.x * 128, n0 = blockIdx.y * 128;
  const int rin = lane >> 3, blk = lane & 7;
  const int r7 = lo & 7;

  f32x4 acc[4][4];
  const f32x4 fz = {0.f, 0.f, 0.f, 0.f};
#pragma unroll
  for (int i = 0; i < 4; ++i)
#pragma unroll
    for (int j = 0; j < 4; ++j) acc[i][j] = fz;

  const u16* gb = B + (size_t)(n0 + 32 * wv + rin) * CDIM + (blk ^ rin) * 8;

  for (int kt = 0; kt < 16; ++kt) {
    const int k0 = kt * 64;
    // ---- A: reg-staged merge (PA+PB)*il, swizzled ds_write ----
#pragma unroll
    for (int i = 0; i < 4; ++i) {
      const int row = 32 * wv + 8 * i + rin;
      const int mg = m0 + row;
      const int t = mg & 2047, bidx = mg >> 11;
      const int bh = bidx * NH + kt;
      const float lA = ML[((size_t)bh << 11) + t];
      const float lB = ML[((size_t)(64 + bh) << 11) + t];
      const float il = 1.0f / (lA + lB);
      const size_t gi = (size_t)mg * CDIM + k0 + blk * 8;
      const short8 pa = *(const short8*)&PA[gi];
      const short8 pb = *(const short8*)&PB[gi];
      float f[8];
#pragma unroll
      for (int e = 0; e < 8; ++e)
        f[e] = (bf2f((u16)pa[e]) + bf2f((u16)pb[e])) * il;
      union { u32x4 w; short8 s8; } v;
#pragma unroll
      for (int j = 0; j < 4; ++j) v.w[j] = cvtpk(f[2 * j], f[2 * j + 1]);
      *(short8*)&As[row][(blk ^ rin) * 8] = v.s8;
    }
    // ---- B: gl_lds, pre-swizzled source ----
#pragma unroll
    for (int i = 0; i < 4; ++i)
      glds16(gb + k0 + (size_t)(8 * i) * CDIM, &Bs[32 * wv + 8 * i][0]);
    __syncthreads();
#pragma unroll
    for (int kk = 0; kk < 2; ++kk) {
      short8 af[4], bf[4];
#pragma unroll
      for (int mi = 0; mi < 4; ++mi)
        af[mi] = *(const short8*)&As[wr * 64 + mi * 16 + lo][(((kk * 4 + lg) ^ r7) * 8)];
#pragma unroll
      for (int ni = 0; ni < 4; ++ni)
        bf[ni] = *(const short8*)&Bs[wc * 64 + ni * 16 + lo][(((kk * 4 + lg) ^ r7) * 8)];
#pragma unroll
      for (int mi = 0; mi < 4; ++mi)
#pragma unroll
        for (int ni = 0; ni < 4; ++ni)
          acc[mi][ni] = __builtin_amdgcn_mfma_f32_16x16x32_bf16(af[mi], bf[ni], acc[mi][ni], 0, 0, 0);
    }
    __syncthreads();
  }

#pragma unroll
  for (int ni = 0; ni < 4; ++ni) {
    const int o = n0 + wc * 64 + ni * 16 + lo;
    const float bv = bias[o];
#pragma unroll
    for (int mi = 0; mi < 4; ++mi)
#pragma unroll
      for (int r = 0; r < 4; ++r)
        Out[(size_t)(m0 + wr * 64 + mi * 16 + lg * 4 + r) * CDIM + o] = acc[mi][ni][r] + bv;
  }
}

extern "C" void kernel_launch(void* const* d_in, const int* in_sizes, int n_in,
                              void* d_out, int out_size, void* d_ws, size_t ws_size,
                              hipStream_t stream) {
  const float* X = (const float*)d_in[0];
  const float* Wqkv = (const float*)d_in[1];
  const float* bqkv = (const float*)d_in[2];
  const float* Wout = (const float*)d_in[3];
  const float* bout = (const float*)d_in[4];
  float* Out = (float*)d_out;

  u16* Xb  = (u16*)d_ws;              // 8,388,608 u16 (reused as PB after qkv)
  u16* W1b = Xb + 8388608;            // 3,145,728 u16 (reused as ML after qkv)
  u16* W2b = W1b + 3145728;           // 1,048,576
  u16* Qb  = W2b + 1048576;           // 8,388,608 (pre-scaled by QSC)
  u16* Kb  = Qb + 8388608;            // 8,388,608
  u16* VTb = Kb + 8388608;            // 8,388,608 (transposed: [bh][d][t])
  u16* Ctx = VTb + 8388608;           // 8,388,608 (PA partial)

  conv_bf16<<<1024, 256, 0, stream>>>(X, Wqkv, Wout, Xb, W1b, W2b);
  qkv_gemm5<<<dim3(32, 24), 512, 0, stream>>>(Xb, W1b, bqkv, Qb, Kb, VTb);
  attn10<<<dim3(1024), 256, 0, stream>>>(Qb, Kb, VTb, Ctx, Xb, (float*)W1b);
  out_gemm3<<<dim3(64, 8), 256, 0, stream>>>(Ctx, Xb, (const float*)W1b, W2b, bout, Out);
}

// Round 16
// 157.592 us; speedup vs baseline: 1.1753x; 1.1753x over previous
//
#include <hip/hip_runtime.h>

typedef __attribute__((ext_vector_type(8))) short short8;
typedef __attribute__((ext_vector_type(4))) float f32x4;
typedef __attribute__((ext_vector_type(16))) float f32x16;
typedef __attribute__((ext_vector_type(4))) unsigned int u32x4;
typedef __attribute__((ext_vector_type(4))) unsigned short u16x4;
typedef unsigned int u32;
typedef unsigned short u16;

#define DEV static __device__ __forceinline__

DEV u16 f2bf(float f) {
  union { float f; u32 u; } c; c.f = f;
  u32 r = (c.u + 0x7fffu + ((c.u >> 16) & 1u)) >> 16;
  return (u16)r;
}
DEV float bf2f(u16 v) {
  union { u32 u; float f; } c; c.u = ((u32)v) << 16;
  return c.f;
}
DEV short8 pack8(float4 a, float4 b) {
  short8 r;
  r[0]=(short)f2bf(a.x); r[1]=(short)f2bf(a.y); r[2]=(short)f2bf(a.z); r[3]=(short)f2bf(a.w);
  r[4]=(short)f2bf(b.x); r[5]=(short)f2bf(b.y); r[6]=(short)f2bf(b.z); r[7]=(short)f2bf(b.w);
  return r;
}
DEV u32 cvtpk(float lo, float hi) {  // packed bf16 pair, RTNE
  u32 r;
  asm("v_cvt_pk_bf16_f32 %0, %1, %2" : "=v"(r) : "v"(lo), "v"(hi));
  return r;
}

// fast exp2: single v_exp_f32 (library exp2f carries range-check overhead)
#if __has_builtin(__builtin_amdgcn_exp2f)
DEV float fexp2(float x) { return __builtin_amdgcn_exp2f(x); }
#else
DEV float fexp2(float x) { return exp2f(x); }
#endif

DEV void glds16(const void* g, void* l) {
  __builtin_amdgcn_global_load_lds((const __attribute__((address_space(1))) u32*)g,
                                   (__attribute__((address_space(3))) u32*)l, 16, 0, 0);
}

DEV f32x16 mfma32(short8 a, short8 b, f32x16 c) {
  return __builtin_amdgcn_mfma_f32_32x32x16_bf16(a, b, c, 0, 0, 0);
}

constexpr int CDIM = 1024, TT = 2048, NH = 16, DK = 64;
// Q pre-scale: 1/sqrt(64) * log2(e)  (softmax runs in exp2 domain)
#define QSC 0.1803368801111601f

// ---------------- fp32 -> bf16 conversion, block-partitioned ---------------
// X: 1,048,576 groups (blocks 0-1023); W1: 393,216 (1024-1407); W2: 131,072
// (1408-1535). 4 groups/thread, coalesced; uniform per-block branch.
__global__ void conv_bf16b(const float* __restrict__ X, const float* __restrict__ W1,
                           const float* __restrict__ W2, u16* __restrict__ Xb,
                           u16* __restrict__ W1b, u16* __restrict__ W2b) {
  const int bid = blockIdx.x;
  const float* s; u16* d; long base;
  if (bid < 1024)      { s = X;  d = Xb;  base = (long)bid * 1024; }
  else if (bid < 1408) { s = W1; d = W1b; base = (long)(bid - 1024) * 1024; }
  else                 { s = W2; d = W2b; base = (long)(bid - 1408) * 1024; }
#pragma unroll
  for (int i = 0; i < 4; ++i) {
    const long j = base + i * 256 + threadIdx.x;
    float4 a = ((const float4*)s)[2 * j];
    float4 b = ((const float4*)s)[2 * j + 1];
    ((short8*)d)[j] = pack8(a, b);
  }
}

// ---------------- QKV GEMM v5 (r13 best, 72.7us): 256x128 tile, 8 waves ----
__global__ void __launch_bounds__(512, 2)
qkv_gemm5(const u16* __restrict__ A, const u16* __restrict__ B,
          const float* __restrict__ bias, u16* __restrict__ Qb,
          u16* __restrict__ Kb, u16* __restrict__ VTb) {
  __shared__ u16 LS[3][3][128][64];  // [buf][chunk: A-lo, A-hi, B][row][col]
  const int tid = threadIdx.x, lane = tid & 63, wid = tid >> 6;
  const int lo = lane & 15, lg = lane >> 4;
  const int wm = wid >> 1, wn = wid & 1;          // wave tile: 64 rows x 64 cols
  const int rin = lane >> 3, blk = lane & 7;
  const int m0 = blockIdx.x * 256, n0 = blockIdx.y * 128;
  const int r7 = lo & 7;

  const u16* gA = A + (size_t)(m0 + wid * 16 + rin) * CDIM + (blk ^ rin) * 8;
  const u16* gB = B + (size_t)(n0 + wid * 16 + rin) * CDIM + (blk ^ rin) * 8;
  u16* lsb = &LS[0][0][wid * 16][0];

#define STGH0(bufi, kt)                                          \
  {                                                              \
    const int k0e = (kt) * 64;                                   \
    u16* lb = lsb + (bufi) * 24576;                              \
    glds16(gA + k0e, lb);                                        \
    glds16(gA + k0e + 8 * CDIM, lb + 512);                       \
    glds16(gB + k0e, lb + 16384);                                \
  }
#define STGH1(bufi, kt)                                          \
  {                                                              \
    const int k0e = (kt) * 64;                                   \
    u16* lb = lsb + (bufi) * 24576;                              \
    glds16(gA + k0e + 128 * CDIM, lb + 8192);                    \
    glds16(gA + k0e + 136 * CDIM, lb + 8704);                    \
    glds16(gB + k0e + 8 * CDIM, lb + 16896);                     \
  }

  f32x4 acc[4][4];
  const f32x4 fz = {0.f, 0.f, 0.f, 0.f};
#pragma unroll
  for (int i = 0; i < 4; ++i)
#pragma unroll
    for (int j = 0; j < 4; ++j) acc[i][j] = fz;

  STGH0(0, 0); STGH1(0, 0);
  STGH0(1, 1); STGH1(1, 1);
  asm volatile("s_waitcnt vmcnt(6)" ::: "memory");
  __builtin_amdgcn_s_barrier();

  int b0 = 0, b1 = 1, b2 = 2;
  for (int T = 0; T < 16; ++T) {
    const u16* pA = &LS[b0][wm >> 1][(wm & 1) * 64][0];
    const u16* pB = &LS[b0][2][wn * 64][0];
    short8 af[4], bfr[4];
    // ================= phase 0 (kk = 0) =================
#pragma unroll
    for (int mi = 0; mi < 4; ++mi)
      af[mi] = *(const short8*)&pA[(mi * 16 + lo) * 64 + ((lg ^ r7) * 8)];
#pragma unroll
    for (int ni = 0; ni < 4; ++ni)
      bfr[ni] = *(const short8*)&pB[(ni * 16 + lo) * 64 + ((lg ^ r7) * 8)];
    if (T < 14) STGH0(b2, T + 2);
    __builtin_amdgcn_sched_barrier(0);
    __builtin_amdgcn_s_barrier();
    asm volatile("s_waitcnt lgkmcnt(0)" ::: "memory");
    __builtin_amdgcn_sched_barrier(0);
    __builtin_amdgcn_s_setprio(1);
#pragma unroll
    for (int mi = 0; mi < 4; ++mi)
#pragma unroll
      for (int ni = 0; ni < 4; ++ni)
        acc[mi][ni] = __builtin_amdgcn_mfma_f32_16x16x32_bf16(af[mi], bfr[ni], acc[mi][ni], 0, 0, 0);
    __builtin_amdgcn_s_setprio(0);
    __builtin_amdgcn_sched_barrier(0);
    __builtin_amdgcn_s_barrier();
    // ================= phase 1 (kk = 1) =================
#pragma unroll
    for (int mi = 0; mi < 4; ++mi)
      af[mi] = *(const short8*)&pA[(mi * 16 + lo) * 64 + (((4 + lg) ^ r7) * 8)];
#pragma unroll
    for (int ni = 0; ni < 4; ++ni)
      bfr[ni] = *(const short8*)&pB[(ni * 16 + lo) * 64 + (((4 + lg) ^ r7) * 8)];
    if (T < 14) STGH1(b2, T + 2);
    __builtin_amdgcn_sched_barrier(0);
    if (T < 14) {
      asm volatile("s_waitcnt vmcnt(6)" ::: "memory");   // gate tile T+1
    } else if (T == 14) {
      asm volatile("s_waitcnt vmcnt(0)" ::: "memory");   // gate tile 15
    }
    __builtin_amdgcn_s_barrier();
    asm volatile("s_waitcnt lgkmcnt(0)" ::: "memory");
    __builtin_amdgcn_sched_barrier(0);
    __builtin_amdgcn_s_setprio(1);
#pragma unroll
    for (int mi = 0; mi < 4; ++mi)
#pragma unroll
      for (int ni = 0; ni < 4; ++ni)
        acc[mi][ni] = __builtin_amdgcn_mfma_f32_16x16x32_bf16(af[mi], bfr[ni], acc[mi][ni], 0, 0, 0);
    __builtin_amdgcn_s_setprio(0);
    __builtin_amdgcn_sched_barrier(0);
    __builtin_amdgcn_s_barrier();
    const int tmp = b0; b0 = b1; b1 = b2; b2 = tmp;
  }
#undef STGH0
#undef STGH1

  // ---- scatter epilogue ----
#pragma unroll
  for (int ni = 0; ni < 4; ++ni) {
    const int o = n0 + wn * 64 + ni * 16 + lo;
    const float bv = bias[o];
    const int hh = o / 192, rem = o - hh * 192, which = rem >> 6, d = rem & 63;
#pragma unroll
    for (int mi = 0; mi < 4; ++mi) {
      const int mb = m0 + wm * 64 + mi * 16 + lg * 4;
      const int bbi = mb >> 11, t0 = mb & 2047;
      const int bh = bbi * NH + hh;
      if (which == 2) {
        u16x4 pk;
#pragma unroll
        for (int r = 0; r < 4; ++r) pk[r] = f2bf(acc[mi][ni][r] + bv);
        *(u16x4*)&VTb[((size_t)bh * DK + d) * TT + t0] = pk;
      } else if (which == 1) {
#pragma unroll
        for (int r = 0; r < 4; ++r)
          Kb[((size_t)bh * TT + t0 + r) * DK + d] = f2bf(acc[mi][ni][r] + bv);
      } else {
#pragma unroll
        for (int r = 0; r < 4; ++r)
          Qb[((size_t)bh * TT + t0 + r) * DK + d] = f2bf((acc[mi][ni][r] + bv) * QSC);
      }
    }
  }
}

// ---------------- Flash attention v10: no-max softmax, 4 blocks/CU ----------
__global__ void __launch_bounds__(256, 4)
attn10(const u16* __restrict__ Qb, const u16* __restrict__ Kb,
       const u16* __restrict__ VTb, u16* __restrict__ PA, u16* __restrict__ PB,
       float* __restrict__ ML) {
  __shared__ u16 Kls[2][64][64];
  __shared__ u16 Vls[2][64][64];
  const int tid = threadIdx.x, lane = tid & 63, wv = tid >> 6;
  const int lq = lane & 31, h = lane >> 5;
  const int id = blockIdx.x;
  const int w = (id & 7) * 128 + (id >> 3);  // logical work index, XCD-chunked
  const int bh = w >> 4;                     // 8 bh per XCD
  const int pj = w & 7;                      // pair index
  const int sp = (w >> 3) & 1;               // kv parity
  const int bb = bh >> 4, head = bh & 15;
  const u16* Qp = Qb + (size_t)bh * TT * DK;
  const u16* Kp = Kb + (size_t)bh * TT * DK;
  const u16* Vp = VTb + (size_t)bh * DK * TT;
  const int rin = lane >> 3, blk = lane & 7;
  u16* PO = sp ? PB : PA;

  const u16* kga = Kp + (size_t)(wv * 16 + rin) * DK + (blk ^ rin) * 8;
  const u16* vga = Vp + (size_t)(wv * 16 + rin) * TT + (blk ^ rin) * 8;
  u16* kls0 = &Kls[0][wv * 16][0];
  u16* vls0 = &Vls[0][wv * 16][0];
  const int lds_half = 64 * 64;  // u16 elems between buf 0 and 1

#define STAGE10(bufi, kvt_)                                                 \
  {                                                                         \
    const int o_ = (bufi) * lds_half;                                       \
    glds16(kga + (size_t)(kvt_) * 4096, kls0 + o_);                         \
    glds16(kga + (size_t)(kvt_) * 4096 + 512, kls0 + o_ + 512);             \
    glds16(vga + (size_t)(kvt_) * 64, vls0 + o_);                           \
    glds16(vga + (size_t)(kvt_) * 64 + 8 * TT, vls0 + o_ + 512);            \
  }

  for (int pi = 0; pi < 2; ++pi) {
    const int qtile = pi ? (15 - pj) : pj;
    const int q0w = qtile * 128 + wv * 32;
    const int qrow = q0w + lq;

    short8 qw[4];
#pragma unroll
    for (int kk = 0; kk < 4; ++kk)
      qw[kk] = *(const short8*)&Qp[(size_t)qrow * DK + kk * 16 + h * 8];

    f32x16 oa0, oa1;
#pragma unroll
    for (int r = 0; r < 16; ++r) { oa0[r] = 0.f; oa1[r] = 0.f; }
    float l_s = 0.f;

    const int nt = 2 * qtile + 2;
    STAGE10(0, sp);
    __syncthreads();
    int buf = 0;
    for (int kvt = sp; kvt < nt; kvt += 2) {
      const int kv0 = kvt * 64;
      if (kvt + 2 < nt) STAGE10(buf ^ 1, kvt + 2);
      if (kv0 <= q0w + 31) {
        f32x16 s0, s1;
#pragma unroll
        for (int r = 0; r < 16; ++r) { s0[r] = 0.f; s1[r] = 0.f; }
        __builtin_amdgcn_s_setprio(1);
#pragma unroll
        for (int kk = 0; kk < 4; ++kk) {
          const short8 kf0 = *(const short8*)&Kls[buf][lq][(((2 * kk + h) ^ (lq & 7)) * 8)];
          const short8 kf1 = *(const short8*)&Kls[buf][32 + lq][(((2 * kk + h) ^ (lq & 7)) * 8)];
          s0 = mfma32(kf0, qw[kk], s0);
          s1 = mfma32(kf1, qw[kk], s1);
        }
        __builtin_amdgcn_s_setprio(0);
        const bool diag = (kv0 + 63 > q0w);
        if (diag) {
          const int lim = qrow - kv0 - 4 * h;
#pragma unroll
          for (int r = 0; r < 16; ++r) {
            const int kl = (r & 3) + 8 * (r >> 2);
            s0[r] = (kl <= lim) ? s0[r] : -1e30f;
            s1[r] = (kl + 32 <= lim) ? s1[r] : -1e30f;
          }
        }
        float rsa = 0.f, rsb = 0.f, rsc = 0.f, rsd = 0.f;
#pragma unroll
        for (int r = 0; r < 16; r += 4) {
          const float a0 = fexp2(s0[r]),     a1 = fexp2(s1[r]);
          const float b0 = fexp2(s0[r + 1]), b1 = fexp2(s1[r + 1]);
          const float c0 = fexp2(s0[r + 2]), c1 = fexp2(s1[r + 2]);
          const float d0 = fexp2(s0[r + 3]), d1 = fexp2(s1[r + 3]);
          s0[r] = a0; s1[r] = a1; s0[r + 1] = b0; s1[r + 1] = b1;
          s0[r + 2] = c0; s1[r + 2] = c1; s0[r + 3] = d0; s1[r + 3] = d1;
          rsa += a0 + a1; rsb += b0 + b1; rsc += c0 + c1; rsd += d0 + d1;
        }
        float rs = (rsa + rsb) + (rsc + rsd);
        rs += __shfl_xor(rs, 32);
        l_s += rs;
#pragma unroll
        for (int s = 0; s < 2; ++s) {
          u32 C[8];
#pragma unroll
          for (int j = 0; j < 8; ++j)
            C[j] = s ? cvtpk(s1[2 * j], s1[2 * j + 1]) : cvtpk(s0[2 * j], s0[2 * j + 1]);
#pragma unroll
          for (int b = 0; b < 2; ++b) {
            const int o = 4 * b;
            const u32 D1 = h ? C[o + 0] : C[o + 2];
            const u32 D2 = h ? C[o + 1] : C[o + 3];
            const u32 R1 = __shfl_xor(D1, 32);
            const u32 R2 = __shfl_xor(D2, 32);
            union { u32x4 w; short8 s8; } pa;
            pa.w[0] = h ? R1 : C[o + 0];
            pa.w[1] = h ? R2 : C[o + 1];
            pa.w[2] = h ? C[o + 2] : R1;
            pa.w[3] = h ? C[o + 3] : R2;
            const int ks = 2 * s + b;
            const short8 vb0 = *(const short8*)&Vls[buf][lq][(((2 * ks + h) ^ (lq & 7)) * 8)];
            const short8 vb1 = *(const short8*)&Vls[buf][32 + lq][(((2 * ks + h) ^ (lq & 7)) * 8)];
            __builtin_amdgcn_s_setprio(1);
            oa0 = mfma32(pa.s8, vb0, oa0);
            oa1 = mfma32(pa.s8, vb1, oa1);
            __builtin_amdgcn_s_setprio(0);
          }
        }
      }
      __syncthreads();
      buf ^= 1;
    }

#pragma unroll
    for (int r = 0; r < 16; ++r) {
      const int t = q0w + (r & 3) + 8 * (r >> 2) + 4 * h;
      const size_t rowb = ((size_t)(bb * TT + t)) * CDIM + head * DK;
      PO[rowb + lq] = f2bf(oa0[r]);
      PO[rowb + 32 + lq] = f2bf(oa1[r]);
    }
    if (h == 0) ML[((size_t)(sp * 64 + bh) << 11) + qrow] = l_s;
    __syncthreads();
  }
#undef STAGE10
}

// ---------------- merge of the two kv-parity partials ----------------------
__global__ void attn_merge(const u16* PA, const u16* PB,
                           const float* __restrict__ ML, u16* Ctx) {
  const int row = blockIdx.x;  // b*2048 + t
  const int b = row >> 11, t = row & 2047;
  const int c = threadIdx.x * 4;
  const int head = c >> 6;
  const int bh = b * NH + head;
  const float lA = ML[((size_t)bh << 11) + t];
  const float lB = ML[((size_t)(64 + bh) << 11) + t];
  const float il = 1.0f / (lA + lB);
  const size_t idx = ((size_t)row) * CDIM + c;
  u16x4 pa = *(const u16x4*)&PA[idx];
  u16x4 pb = *(const u16x4*)&PB[idx];
  u16x4 o;
#pragma unroll
  for (int e = 0; e < 4; ++e) o[e] = f2bf((bf2f(pa[e]) + bf2f(pb[e])) * il);
  *(u16x4*)&Ctx[idx] = o;
}

// ---------------- Output GEMM v4: m97 structure + proven LDS swizzle --------
__global__ void out_gemm4(const u16* __restrict__ A, const u16* __restrict__ B,
                          const float* __restrict__ bias, float* __restrict__ Out) {
  __shared__ u16 As[128][64];
  __shared__ u16 Bs[128][64];
  const int tid = threadIdx.x, lane = tid & 63, wv = tid >> 6;
  const int wr = wv >> 1, wc = wv & 1, lo = lane & 15, lg = lane >> 4;
  const int m0 = blockIdx.x * 128, n0 = blockIdx.y * 128;
  const int rin = lane >> 3, blk = lane & 7;
  const int r7 = lo & 7;

  f32x4 acc[4][4];
  const f32x4 fz = {0.f, 0.f, 0.f, 0.f};
#pragma unroll
  for (int i = 0; i < 4; ++i)
#pragma unroll
    for (int j = 0; j < 4; ++j) acc[i][j] = fz;

  const u16* ga = A + (size_t)(m0 + 32 * wv + rin) * CDIM + (blk ^ rin) * 8;
  const u16* gb = B + (size_t)(n0 + 32 * wv + rin) * CDIM + (blk ^ rin) * 8;

  for (int k0 = 0; k0 < CDIM; k0 += 64) {
#pragma unroll
    for (int i = 0; i < 4; ++i) glds16(ga + k0 + (size_t)(8 * i) * CDIM, &As[32 * wv + 8 * i][0]);
#pragma unroll
    for (int i = 0; i < 4; ++i) glds16(gb + k0 + (size_t)(8 * i) * CDIM, &Bs[32 * wv + 8 * i][0]);
    __syncthreads();
#pragma unroll
    for (int kk = 0; kk < 2; ++kk) {
      short8 af[4], bf[4];
#pragma unroll
      for (int mi = 0; mi < 4; ++mi)
        af[mi] = *(const short8*)&As[wr * 64 + mi * 16 + lo][(((kk * 4 + lg) ^ r7) * 8)];
#pragma unroll
      for (int ni = 0; ni < 4; ++ni)
        bf[ni] = *(const short8*)&Bs[wc * 64 + ni * 16 + lo][(((kk * 4 + lg) ^ r7) * 8)];
#pragma unroll
      for (int mi = 0; mi < 4; ++mi)
#pragma unroll
        for (int ni = 0; ni < 4; ++ni)
          acc[mi][ni] = __builtin_amdgcn_mfma_f32_16x16x32_bf16(af[mi], bf[ni], acc[mi][ni], 0, 0, 0);
    }
    __syncthreads();
  }

#pragma unroll
  for (int ni = 0; ni < 4; ++ni) {
    const int o = n0 + wc * 64 + ni * 16 + lo;
    const float bv = bias[o];
#pragma unroll
    for (int mi = 0; mi < 4; ++mi)
#pragma unroll
      for (int r = 0; r < 4; ++r)
        Out[(size_t)(m0 + wr * 64 + mi * 16 + lg * 4 + r) * CDIM + o] = acc[mi][ni][r] + bv;
  }
}

extern "C" void kernel_launch(void* const* d_in, const int* in_sizes, int n_in,
                              void* d_out, int out_size, void* d_ws, size_t ws_size,
                              hipStream_t stream) {
  const float* X = (const float*)d_in[0];
  const float* Wqkv = (const float*)d_in[1];
  const float* bqkv = (const float*)d_in[2];
  const float* Wout = (const float*)d_in[3];
  const float* bout = (const float*)d_in[4];
  float* Out = (float*)d_out;

  u16* Xb  = (u16*)d_ws;              // 8,388,608 u16 (reused as PB after qkv)
  u16* W1b = Xb + 8388608;            // 3,145,728 u16 (reused as ML after qkv)
  u16* W2b = W1b + 3145728;           // 1,048,576
  u16* Qb  = W2b + 1048576;           // 8,388,608 (pre-scaled by QSC)
  u16* Kb  = Qb + 8388608;            // 8,388,608
  u16* VTb = Kb + 8388608;            // 8,388,608 (transposed: [bh][d][t])
  u16* Ctx = VTb + 8388608;           // 8,388,608 (PA partial, then merged in-place)

  conv_bf16b<<<1536, 256, 0, stream>>>(X, Wqkv, Wout, Xb, W1b, W2b);
  qkv_gemm5<<<dim3(32, 24), 512, 0, stream>>>(Xb, W1b, bqkv, Qb, Kb, VTb);
  attn10<<<dim3(1024), 256, 0, stream>>>(Qb, Kb, VTb, Ctx, Xb, (float*)W1b);
  attn_merge<<<8192, 256, 0, stream>>>(Ctx, Xb, (const float*)W1b, Ctx);
  out_gemm4<<<dim3(64, 8), 256, 0, stream>>>(Ctx, W2b, bout, Out);
}

// Round 17
// 156.570 us; speedup vs baseline: 1.1830x; 1.0065x over previous
//
#include <hip/hip_runtime.h>

typedef __attribute__((ext_vector_type(8))) short short8;
typedef __attribute__((ext_vector_type(4))) float f32x4;
typedef __attribute__((ext_vector_type(16))) float f32x16;
typedef __attribute__((ext_vector_type(4))) unsigned int u32x4;
typedef __attribute__((ext_vector_type(4))) unsigned short u16x4;
typedef unsigned int u32;
typedef unsigned short u16;

#define DEV static __device__ __forceinline__

DEV u16 f2bf(float f) {
  union { float f; u32 u; } c; c.f = f;
  u32 r = (c.u + 0x7fffu + ((c.u >> 16) & 1u)) >> 16;
  return (u16)r;
}
DEV float bf2f(u16 v) {
  union { u32 u; float f; } c; c.u = ((u32)v) << 16;
  return c.f;
}
DEV short8 pack8(float4 a, float4 b) {
  short8 r;
  r[0]=(short)f2bf(a.x); r[1]=(short)f2bf(a.y); r[2]=(short)f2bf(a.z); r[3]=(short)f2bf(a.w);
  r[4]=(short)f2bf(b.x); r[5]=(short)f2bf(b.y); r[6]=(short)f2bf(b.z); r[7]=(short)f2bf(b.w);
  return r;
}
DEV u32 cvtpk(float lo, float hi) {  // packed bf16 pair, RTNE
  u32 r;
  asm("v_cvt_pk_bf16_f32 %0, %1, %2" : "=v"(r) : "v"(lo), "v"(hi));
  return r;
}

// fast exp2: single v_exp_f32 (library exp2f carries range-check overhead)
#if __has_builtin(__builtin_amdgcn_exp2f)
DEV float fexp2(float x) { return __builtin_amdgcn_exp2f(x); }
#else
DEV float fexp2(float x) { return exp2f(x); }
#endif

DEV void glds16(const void* g, void* l) {
  __builtin_amdgcn_global_load_lds((const __attribute__((address_space(1))) u32*)g,
                                   (__attribute__((address_space(3))) u32*)l, 16, 0, 0);
}

DEV f32x16 mfma32(short8 a, short8 b, f32x16 c) {
  return __builtin_amdgcn_mfma_f32_32x32x16_bf16(a, b, c, 0, 0, 0);
}

constexpr int CDIM = 1024, TT = 2048, NH = 16, DK = 64;
// Q pre-scale: 1/sqrt(64) * log2(e)  (softmax runs in exp2 domain)
#define QSC 0.1803368801111601f

// ---------------- fp32 -> bf16 conversion, block-partitioned ---------------
__global__ void conv_bf16b(const float* __restrict__ X, const float* __restrict__ W1,
                           const float* __restrict__ W2, u16* __restrict__ Xb,
                           u16* __restrict__ W1b, u16* __restrict__ W2b) {
  const int bid = blockIdx.x;
  const float* s; u16* d; long base;
  if (bid < 1024)      { s = X;  d = Xb;  base = (long)bid * 1024; }
  else if (bid < 1408) { s = W1; d = W1b; base = (long)(bid - 1024) * 1024; }
  else                 { s = W2; d = W2b; base = (long)(bid - 1408) * 1024; }
#pragma unroll
  for (int i = 0; i < 4; ++i) {
    const long j = base + i * 256 + threadIdx.x;
    float4 a = ((const float4*)s)[2 * j];
    float4 b = ((const float4*)s)[2 * j + 1];
    ((short8*)d)[j] = pack8(a, b);
  }
}

// ---------------- QKV GEMM v8: gemm5 schedule + 32x32x16 MFMA ---------------
// Same 256x128 tile, 8 waves, 3-buffer counted-vmcnt phases; inner product
// uses mfma_f32_32x32x16_bf16 (half the MFMA instructions, faster shape).
// Wave tile 64x64 = 2x2 blocks of 32x32; acc[mb][nb] = f32x16.
__global__ void __launch_bounds__(512, 2)
qkv_gemm8(const u16* __restrict__ A, const u16* __restrict__ B,
          const float* __restrict__ bias, u16* __restrict__ Qb,
          u16* __restrict__ Kb, u16* __restrict__ VTb) {
  __shared__ u16 LS[3][3][128][64];  // [buf][chunk: A-lo, A-hi, B][row][col]
  const int tid = threadIdx.x, lane = tid & 63, wid = tid >> 6;
  const int l31 = lane & 31, h2 = lane >> 5;
  const int wm = wid >> 1, wn = wid & 1;          // wave tile: 64 rows x 64 cols
  const int rin = lane >> 3, blk = lane & 7;
  const int m0 = blockIdx.x * 256, n0 = blockIdx.y * 128;
  const int rq = lane & 7;                         // (row&7) for swizzled reads

  const u16* gA = A + (size_t)(m0 + wid * 16 + rin) * CDIM + (blk ^ rin) * 8;
  const u16* gB = B + (size_t)(n0 + wid * 16 + rin) * CDIM + (blk ^ rin) * 8;
  u16* lsb = &LS[0][0][wid * 16][0];

#define STGH0(bufi, kt)                                          \
  {                                                              \
    const int k0e = (kt) * 64;                                   \
    u16* lb = lsb + (bufi) * 24576;                              \
    glds16(gA + k0e, lb);                                        \
    glds16(gA + k0e + 8 * CDIM, lb + 512);                       \
    glds16(gB + k0e, lb + 16384);                                \
  }
#define STGH1(bufi, kt)                                          \
  {                                                              \
    const int k0e = (kt) * 64;                                   \
    u16* lb = lsb + (bufi) * 24576;                              \
    glds16(gA + k0e + 128 * CDIM, lb + 8192);                    \
    glds16(gA + k0e + 136 * CDIM, lb + 8704);                    \
    glds16(gB + k0e + 8 * CDIM, lb + 16896);                     \
  }

  f32x16 acc[2][2];
#pragma unroll
  for (int i = 0; i < 2; ++i)
#pragma unroll
    for (int j = 0; j < 2; ++j)
#pragma unroll
      for (int r = 0; r < 16; ++r) acc[i][j][r] = 0.f;

  STGH0(0, 0); STGH1(0, 0);
  STGH0(1, 1); STGH1(1, 1);
  asm volatile("s_waitcnt vmcnt(6)" ::: "memory");
  __builtin_amdgcn_s_barrier();

  int b0 = 0, b1 = 1, b2 = 2;
  for (int T = 0; T < 16; ++T) {
    const u16* pA = &LS[b0][wm >> 1][(wm & 1) * 64][0];
    const u16* pB = &LS[b0][2][wn * 64][0];
    short8 af[2][2], bfr[2][2];   // [mb|nb][kk2]
    // ================= phase 0 (kk = 0,1) =================
#pragma unroll
    for (int kk2 = 0; kk2 < 2; ++kk2) {
      const int j = 2 * kk2 + h2;
#pragma unroll
      for (int mb = 0; mb < 2; ++mb)
        af[mb][kk2] = *(const short8*)&pA[(mb * 32 + l31) * 64 + ((j ^ rq) * 8)];
#pragma unroll
      for (int nb = 0; nb < 2; ++nb)
        bfr[nb][kk2] = *(const short8*)&pB[(nb * 32 + l31) * 64 + ((j ^ rq) * 8)];
    }
    if (T < 14) STGH0(b2, T + 2);
    __builtin_amdgcn_sched_barrier(0);
    __builtin_amdgcn_s_barrier();
    asm volatile("s_waitcnt lgkmcnt(0)" ::: "memory");
    __builtin_amdgcn_sched_barrier(0);
    __builtin_amdgcn_s_setprio(1);
#pragma unroll
    for (int kk2 = 0; kk2 < 2; ++kk2)
#pragma unroll
      for (int mb = 0; mb < 2; ++mb)
#pragma unroll
        for (int nb = 0; nb < 2; ++nb)
          acc[mb][nb] = mfma32(af[mb][kk2], bfr[nb][kk2], acc[mb][nb]);
    __builtin_amdgcn_s_setprio(0);
    __builtin_amdgcn_sched_barrier(0);
    __builtin_amdgcn_s_barrier();
    // ================= phase 1 (kk = 2,3) =================
#pragma unroll
    for (int kk2 = 0; kk2 < 2; ++kk2) {
      const int j = 4 + 2 * kk2 + h2;
#pragma unroll
      for (int mb = 0; mb < 2; ++mb)
        af[mb][kk2] = *(const short8*)&pA[(mb * 32 + l31) * 64 + ((j ^ rq) * 8)];
#pragma unroll
      for (int nb = 0; nb < 2; ++nb)
        bfr[nb][kk2] = *(const short8*)&pB[(nb * 32 + l31) * 64 + ((j ^ rq) * 8)];
    }
    if (T < 14) STGH1(b2, T + 2);
    __builtin_amdgcn_sched_barrier(0);
    if (T < 14) {
      asm volatile("s_waitcnt vmcnt(6)" ::: "memory");   // gate tile T+1
    } else if (T == 14) {
      asm volatile("s_waitcnt vmcnt(0)" ::: "memory");   // gate tile 15
    }
    __builtin_amdgcn_s_barrier();
    asm volatile("s_waitcnt lgkmcnt(0)" ::: "memory");
    __builtin_amdgcn_sched_barrier(0);
    __builtin_amdgcn_s_setprio(1);
#pragma unroll
    for (int kk2 = 0; kk2 < 2; ++kk2)
#pragma unroll
      for (int mb = 0; mb < 2; ++mb)
#pragma unroll
        for (int nb = 0; nb < 2; ++nb)
          acc[mb][nb] = mfma32(af[mb][kk2], bfr[nb][kk2], acc[mb][nb]);
    __builtin_amdgcn_s_setprio(0);
    __builtin_amdgcn_sched_barrier(0);
    __builtin_amdgcn_s_barrier();
    const int tmp = b0; b0 = b1; b1 = b2; b2 = tmp;
  }
#undef STGH0
#undef STGH1

  // ---- scatter epilogue (32x32 C/D: col = n-base + l31, row per reg) ----
#pragma unroll
  for (int nb = 0; nb < 2; ++nb) {
    const int o = n0 + wn * 64 + nb * 32 + l31;
    const float bv = bias[o];
    const int hh = o / 192, rem = o - hh * 192, which = rem >> 6, d = rem & 63;
#pragma unroll
    for (int mb = 0; mb < 2; ++mb) {
      const int mbase = m0 + wm * 64 + mb * 32;
      const int bbi = mbase >> 11;           // whole 256-row tile is one batch
      const int bh = bbi * NH + hh;
#pragma unroll
      for (int g = 0; g < 4; ++g) {
        const int t0 = (mbase & 2047) + 8 * g + 4 * h2;  // regs 4g..4g+3 -> t0..t0+3
        if (which == 2) {
          u16x4 pk;
#pragma unroll
          for (int j = 0; j < 4; ++j) pk[j] = f2bf(acc[mb][nb][4 * g + j] + bv);
          *(u16x4*)&VTb[((size_t)bh * DK + d) * TT + t0] = pk;
        } else if (which == 1) {
#pragma unroll
          for (int j = 0; j < 4; ++j)
            Kb[((size_t)bh * TT + t0 + j) * DK + d] = f2bf(acc[mb][nb][4 * g + j] + bv);
        } else {
#pragma unroll
          for (int j = 0; j < 4; ++j)
            Qb[((size_t)bh * TT + t0 + j) * DK + d] = f2bf((acc[mb][nb][4 * g + j] + bv) * QSC);
        }
      }
    }
  }
}

// ---------------- Flash attention v10: no-max softmax, 4 blocks/CU ----------
__global__ void __launch_bounds__(256, 4)
attn10(const u16* __restrict__ Qb, const u16* __restrict__ Kb,
       const u16* __restrict__ VTb, u16* __restrict__ PA, u16* __restrict__ PB,
       float* __restrict__ ML) {
  __shared__ u16 Kls[2][64][64];
  __shared__ u16 Vls[2][64][64];
  const int tid = threadIdx.x, lane = tid & 63, wv = tid >> 6;
  const int lq = lane & 31, h = lane >> 5;
  const int id = blockIdx.x;
  const int w = (id & 7) * 128 + (id >> 3);  // logical work index, XCD-chunked
  const int bh = w >> 4;                     // 8 bh per XCD
  const int pj = w & 7;                      // pair index
  const int sp = (w >> 3) & 1;               // kv parity
  const int bb = bh >> 4, head = bh & 15;
  const u16* Qp = Qb + (size_t)bh * TT * DK;
  const u16* Kp = Kb + (size_t)bh * TT * DK;
  const u16* Vp = VTb + (size_t)bh * DK * TT;
  const int rin = lane >> 3, blk = lane & 7;
  u16* PO = sp ? PB : PA;

  const u16* kga = Kp + (size_t)(wv * 16 + rin) * DK + (blk ^ rin) * 8;
  const u16* vga = Vp + (size_t)(wv * 16 + rin) * TT + (blk ^ rin) * 8;
  u16* kls0 = &Kls[0][wv * 16][0];
  u16* vls0 = &Vls[0][wv * 16][0];
  const int lds_half = 64 * 64;  // u16 elems between buf 0 and 1

#define STAGE10(bufi, kvt_)                                                 \
  {                                                                         \
    const int o_ = (bufi) * lds_half;                                       \
    glds16(kga + (size_t)(kvt_) * 4096, kls0 + o_);                         \
    glds16(kga + (size_t)(kvt_) * 4096 + 512, kls0 + o_ + 512);             \
    glds16(vga + (size_t)(kvt_) * 64, vls0 + o_);                           \
    glds16(vga + (size_t)(kvt_) * 64 + 8 * TT, vls0 + o_ + 512);            \
  }

  for (int pi = 0; pi < 2; ++pi) {
    const int qtile = pi ? (15 - pj) : pj;
    const int q0w = qtile * 128 + wv * 32;
    const int qrow = q0w + lq;

    short8 qw[4];
#pragma unroll
    for (int kk = 0; kk < 4; ++kk)
      qw[kk] = *(const short8*)&Qp[(size_t)qrow * DK + kk * 16 + h * 8];

    f32x16 oa0, oa1;
#pragma unroll
    for (int r = 0; r < 16; ++r) { oa0[r] = 0.f; oa1[r] = 0.f; }
    float l_s = 0.f;

    const int nt = 2 * qtile + 2;
    STAGE10(0, sp);
    __syncthreads();
    int buf = 0;
    for (int kvt = sp; kvt < nt; kvt += 2) {
      const int kv0 = kvt * 64;
      if (kvt + 2 < nt) STAGE10(buf ^ 1, kvt + 2);
      if (kv0 <= q0w + 31) {
        f32x16 s0, s1;
#pragma unroll
        for (int r = 0; r < 16; ++r) { s0[r] = 0.f; s1[r] = 0.f; }
        __builtin_amdgcn_s_setprio(1);
#pragma unroll
        for (int kk = 0; kk < 4; ++kk) {
          const short8 kf0 = *(const short8*)&Kls[buf][lq][(((2 * kk + h) ^ (lq & 7)) * 8)];
          const short8 kf1 = *(const short8*)&Kls[buf][32 + lq][(((2 * kk + h) ^ (lq & 7)) * 8)];
          s0 = mfma32(kf0, qw[kk], s0);
          s1 = mfma32(kf1, qw[kk], s1);
        }
        __builtin_amdgcn_s_setprio(0);
        const bool diag = (kv0 + 63 > q0w);
        if (diag) {
          const int lim = qrow - kv0 - 4 * h;
#pragma unroll
          for (int r = 0; r < 16; ++r) {
            const int kl = (r & 3) + 8 * (r >> 2);
            s0[r] = (kl <= lim) ? s0[r] : -1e30f;
            s1[r] = (kl + 32 <= lim) ? s1[r] : -1e30f;
          }
        }
        float rsa = 0.f, rsb = 0.f, rsc = 0.f, rsd = 0.f;
#pragma unroll
        for (int r = 0; r < 16; r += 4) {
          const float a0 = fexp2(s0[r]),     a1 = fexp2(s1[r]);
          const float b0 = fexp2(s0[r + 1]), b1 = fexp2(s1[r + 1]);
          const float c0 = fexp2(s0[r + 2]), c1 = fexp2(s1[r + 2]);
          const float d0 = fexp2(s0[r + 3]), d1 = fexp2(s1[r + 3]);
          s0[r] = a0; s1[r] = a1; s0[r + 1] = b0; s1[r + 1] = b1;
          s0[r + 2] = c0; s1[r + 2] = c1; s0[r + 3] = d0; s1[r + 3] = d1;
          rsa += a0 + a1; rsb += b0 + b1; rsc += c0 + c1; rsd += d0 + d1;
        }
        float rs = (rsa + rsb) + (rsc + rsd);
        rs += __shfl_xor(rs, 32);
        l_s += rs;
#pragma unroll
        for (int s = 0; s < 2; ++s) {
          u32 C[8];
#pragma unroll
          for (int j = 0; j < 8; ++j)
            C[j] = s ? cvtpk(s1[2 * j], s1[2 * j + 1]) : cvtpk(s0[2 * j], s0[2 * j + 1]);
#pragma unroll
          for (int b = 0; b < 2; ++b) {
            const int o = 4 * b;
            const u32 D1 = h ? C[o + 0] : C[o + 2];
            const u32 D2 = h ? C[o + 1] : C[o + 3];
            const u32 R1 = __shfl_xor(D1, 32);
            const u32 R2 = __shfl_xor(D2, 32);
            union { u32x4 w; short8 s8; } pa;
            pa.w[0] = h ? R1 : C[o + 0];
            pa.w[1] = h ? R2 : C[o + 1];
            pa.w[2] = h ? C[o + 2] : R1;
            pa.w[3] = h ? C[o + 3] : R2;
            const int ks = 2 * s + b;
            const short8 vb0 = *(const short8*)&Vls[buf][lq][(((2 * ks + h) ^ (lq & 7)) * 8)];
            const short8 vb1 = *(const short8*)&Vls[buf][32 + lq][(((2 * ks + h) ^ (lq & 7)) * 8)];
            __builtin_amdgcn_s_setprio(1);
            oa0 = mfma32(pa.s8, vb0, oa0);
            oa1 = mfma32(pa.s8, vb1, oa1);
            __builtin_amdgcn_s_setprio(0);
          }
        }
      }
      __syncthreads();
      buf ^= 1;
    }

#pragma unroll
    for (int r = 0; r < 16; ++r) {
      const int t = q0w + (r & 3) + 8 * (r >> 2) + 4 * h;
      const size_t rowb = ((size_t)(bb * TT + t)) * CDIM + head * DK;
      PO[rowb + lq] = f2bf(oa0[r]);
      PO[rowb + 32 + lq] = f2bf(oa1[r]);
    }
    if (h == 0) ML[((size_t)(sp * 64 + bh) << 11) + qrow] = l_s;
    __syncthreads();
  }
#undef STAGE10
}

// ---------------- merge of the two kv-parity partials ----------------------
__global__ void attn_merge(const u16* PA, const u16* PB,
                           const float* __restrict__ ML, u16* Ctx) {
  const int row = blockIdx.x;  // b*2048 + t
  const int b = row >> 11, t = row & 2047;
  const int c = threadIdx.x * 4;
  const int head = c >> 6;
  const int bh = b * NH + head;
  const float lA = ML[((size_t)bh << 11) + t];
  const float lB = ML[((size_t)(64 + bh) << 11) + t];
  const float il = 1.0f / (lA + lB);
  const size_t idx = ((size_t)row) * CDIM + c;
  u16x4 pa = *(const u16x4*)&PA[idx];
  u16x4 pb = *(const u16x4*)&PB[idx];
  u16x4 o;
#pragma unroll
  for (int e = 0; e < 4; ++e) o[e] = f2bf((bf2f(pa[e]) + bf2f(pb[e])) * il);
  *(u16x4*)&Ctx[idx] = o;
}

// ---------------- Output GEMM v4: m97 structure + proven LDS swizzle --------
__global__ void out_gemm4(const u16* __restrict__ A, const u16* __restrict__ B,
                          const float* __restrict__ bias, float* __restrict__ Out) {
  __shared__ u16 As[128][64];
  __shared__ u16 Bs[128][64];
  const int tid = threadIdx.x, lane = tid & 63, wv = tid >> 6;
  const int wr = wv >> 1, wc = wv & 1, lo = lane & 15, lg = lane >> 4;
  const int m0 = blockIdx.x * 128, n0 = blockIdx.y * 128;
  const int rin = lane >> 3, blk = lane & 7;
  const int r7 = lo & 7;

  f32x4 acc[4][4];
  const f32x4 fz = {0.f, 0.f, 0.f, 0.f};
#pragma unroll
  for (int i = 0; i < 4; ++i)
#pragma unroll
    for (int j = 0; j < 4; ++j) acc[i][j] = fz;

  const u16* ga = A + (size_t)(m0 + 32 * wv + rin) * CDIM + (blk ^ rin) * 8;
  const u16* gb = B + (size_t)(n0 + 32 * wv + rin) * CDIM + (blk ^ rin) * 8;

  for (int k0 = 0; k0 < CDIM; k0 += 64) {
#pragma unroll
    for (int i = 0; i < 4; ++i) glds16(ga + k0 + (size_t)(8 * i) * CDIM, &As[32 * wv + 8 * i][0]);
#pragma unroll
    for (int i = 0; i < 4; ++i) glds16(gb + k0 + (size_t)(8 * i) * CDIM, &Bs[32 * wv + 8 * i][0]);
    __syncthreads();
#pragma unroll
    for (int kk = 0; kk < 2; ++kk) {
      short8 af[4], bf[4];
#pragma unroll
      for (int mi = 0; mi < 4; ++mi)
        af[mi] = *(const short8*)&As[wr * 64 + mi * 16 + lo][(((kk * 4 + lg) ^ r7) * 8)];
#pragma unroll
      for (int ni = 0; ni < 4; ++ni)
        bf[ni] = *(const short8*)&Bs[wc * 64 + ni * 16 + lo][(((kk * 4 + lg) ^ r7) * 8)];
#pragma unroll
      for (int mi = 0; mi < 4; ++mi)
#pragma unroll
        for (int ni = 0; ni < 4; ++ni)
          acc[mi][ni] = __builtin_amdgcn_mfma_f32_16x16x32_bf16(af[mi], bf[ni], acc[mi][ni], 0, 0, 0);
    }
    __syncthreads();
  }

#pragma unroll
  for (int ni = 0; ni < 4; ++ni) {
    const int o = n0 + wc * 64 + ni * 16 + lo;
    const float bv = bias[o];
#pragma unroll
    for (int mi = 0; mi < 4; ++mi)
#pragma unroll
      for (int r = 0; r < 4; ++r)
        Out[(size_t)(m0 + wr * 64 + mi * 16 + lg * 4 + r) * CDIM + o] = acc[mi][ni][r] + bv;
  }
}

extern "C" void kernel_launch(void* const* d_in, const int* in_sizes, int n_in,
                              void* d_out, int out_size, void* d_ws, size_t ws_size,
                              hipStream_t stream) {
  const float* X = (const float*)d_in[0];
  const float* Wqkv = (const float*)d_in[1];
  const float* bqkv = (const float*)d_in[2];
  const float* Wout = (const float*)d_in[3];
  const float* bout = (const float*)d_in[4];
  float* Out = (float*)d_out;

  u16* Xb  = (u16*)d_ws;              // 8,388,608 u16 (reused as PB after qkv)
  u16* W1b = Xb + 8388608;            // 3,145,728 u16 (reused as ML after qkv)
  u16* W2b = W1b + 3145728;           // 1,048,576
  u16* Qb  = W2b + 1048576;           // 8,388,608 (pre-scaled by QSC)
  u16* Kb  = Qb + 8388608;            // 8,388,608
  u16* VTb = Kb + 8388608;            // 8,388,608 (transposed: [bh][d][t])
  u16* Ctx = VTb + 8388608;           // 8,388,608 (PA partial, then merged in-place)

  conv_bf16b<<<1536, 256, 0, stream>>>(X, Wqkv, Wout, Xb, W1b, W2b);
  qkv_gemm8<<<dim3(32, 24), 512, 0, stream>>>(Xb, W1b, bqkv, Qb, Kb, VTb);
  attn10<<<dim3(1024), 256, 0, stream>>>(Qb, Kb, VTb, Ctx, Xb, (float*)W1b);
  attn_merge<<<8192, 256, 0, stream>>>(Ctx, Xb, (const float*)W1b, Ctx);
  out_gemm4<<<dim3(64, 8), 256, 0, stream>>>(Ctx, W2b, bout, Out);
}

// Round 18
// 150.872 us; speedup vs baseline: 1.2277x; 1.0378x over previous
//
#include <hip/hip_runtime.h>

typedef __attribute__((ext_vector_type(8))) short short8;
typedef __attribute__((ext_vector_type(4))) float f32x4;
typedef __attribute__((ext_vector_type(16))) float f32x16;
typedef __attribute__((ext_vector_type(4))) unsigned int u32x4;
typedef __attribute__((ext_vector_type(4))) unsigned short u16x4;
typedef unsigned int u32;
typedef unsigned short u16;

#define DEV static __device__ __forceinline__

DEV u16 f2bf(float f) {
  union { float f; u32 u; } c; c.f = f;
  u32 r = (c.u + 0x7fffu + ((c.u >> 16) & 1u)) >> 16;
  return (u16)r;
}
DEV float bf2f(u16 v) {
  union { u32 u; float f; } c; c.u = ((u32)v) << 16;
  return c.f;
}
DEV short8 pack8(float4 a, float4 b) {
  short8 r;
  r[0]=(short)f2bf(a.x); r[1]=(short)f2bf(a.y); r[2]=(short)f2bf(a.z); r[3]=(short)f2bf(a.w);
  r[4]=(short)f2bf(b.x); r[5]=(short)f2bf(b.y); r[6]=(short)f2bf(b.z); r[7]=(short)f2bf(b.w);
  return r;
}
DEV u32 cvtpk(float lo, float hi) {  // packed bf16 pair, RTNE
  u32 r;
  asm("v_cvt_pk_bf16_f32 %0, %1, %2" : "=v"(r) : "v"(lo), "v"(hi));
  return r;
}

// fast exp2: single v_exp_f32 (library exp2f carries range-check overhead)
#if __has_builtin(__builtin_amdgcn_exp2f)
DEV float fexp2(float x) { return __builtin_amdgcn_exp2f(x); }
#else
DEV float fexp2(float x) { return exp2f(x); }
#endif

DEV void glds16(const void* g, void* l) {
  __builtin_amdgcn_global_load_lds((const __attribute__((address_space(1))) u32*)g,
                                   (__attribute__((address_space(3))) u32*)l, 16, 0, 0);
}

DEV f32x16 mfma32(short8 a, short8 b, f32x16 c) {
  return __builtin_amdgcn_mfma_f32_32x32x16_bf16(a, b, c, 0, 0, 0);
}

constexpr int CDIM = 1024, TT = 2048, NH = 16, DK = 64;
// Q pre-scale: 1/sqrt(64) * log2(e)  (softmax runs in exp2 domain)
#define QSC 0.1803368801111601f

// ---------------- fp32 -> bf16 conversion, block-partitioned ---------------
__global__ void conv_bf16b(const float* __restrict__ X, const float* __restrict__ W1,
                           const float* __restrict__ W2, u16* __restrict__ Xb,
                           u16* __restrict__ W1b, u16* __restrict__ W2b) {
  const int bid = blockIdx.x;
  const float* s; u16* d; long base;
  if (bid < 1024)      { s = X;  d = Xb;  base = (long)bid * 1024; }
  else if (bid < 1408) { s = W1; d = W1b; base = (long)(bid - 1024) * 1024; }
  else                 { s = W2; d = W2b; base = (long)(bid - 1408) * 1024; }
#pragma unroll
  for (int i = 0; i < 4; ++i) {
    const long j = base + i * 256 + threadIdx.x;
    float4 a = ((const float4*)s)[2 * j];
    float4 b = ((const float4*)s)[2 * j + 1];
    ((short8*)d)[j] = pack8(a, b);
  }
}

// ---------------- QKV GEMM v9: out_gemm4 body (128x128, 4 waves, 32KB LDS,
// swizzled) + scatter epilogue. High occupancy (up to 5 blocks/CU) + TLP.
__global__ void qkv_gemm9(const u16* __restrict__ A, const u16* __restrict__ B,
                          const float* __restrict__ bias, u16* __restrict__ Qb,
                          u16* __restrict__ Kb, u16* __restrict__ VTb) {
  __shared__ u16 As[128][64];
  __shared__ u16 Bs[128][64];
  const int tid = threadIdx.x, lane = tid & 63, wv = tid >> 6;
  const int wr = wv >> 1, wc = wv & 1, lo = lane & 15, lg = lane >> 4;
  const int m0 = blockIdx.x * 128, n0 = blockIdx.y * 128;
  const int rin = lane >> 3, blk = lane & 7;
  const int r7 = lo & 7;

  f32x4 acc[4][4];
  const f32x4 fz = {0.f, 0.f, 0.f, 0.f};
#pragma unroll
  for (int i = 0; i < 4; ++i)
#pragma unroll
    for (int j = 0; j < 4; ++j) acc[i][j] = fz;

  const u16* ga = A + (size_t)(m0 + 32 * wv + rin) * CDIM + (blk ^ rin) * 8;
  const u16* gb = B + (size_t)(n0 + 32 * wv + rin) * CDIM + (blk ^ rin) * 8;

  for (int k0 = 0; k0 < CDIM; k0 += 64) {
#pragma unroll
    for (int i = 0; i < 4; ++i) glds16(ga + k0 + (size_t)(8 * i) * CDIM, &As[32 * wv + 8 * i][0]);
#pragma unroll
    for (int i = 0; i < 4; ++i) glds16(gb + k0 + (size_t)(8 * i) * CDIM, &Bs[32 * wv + 8 * i][0]);
    __syncthreads();
#pragma unroll
    for (int kk = 0; kk < 2; ++kk) {
      short8 af[4], bf[4];
#pragma unroll
      for (int mi = 0; mi < 4; ++mi)
        af[mi] = *(const short8*)&As[wr * 64 + mi * 16 + lo][(((kk * 4 + lg) ^ r7) * 8)];
#pragma unroll
      for (int ni = 0; ni < 4; ++ni)
        bf[ni] = *(const short8*)&Bs[wc * 64 + ni * 16 + lo][(((kk * 4 + lg) ^ r7) * 8)];
#pragma unroll
      for (int mi = 0; mi < 4; ++mi)
#pragma unroll
        for (int ni = 0; ni < 4; ++ni)
          acc[mi][ni] = __builtin_amdgcn_mfma_f32_16x16x32_bf16(af[mi], bf[ni], acc[mi][ni], 0, 0, 0);
    }
    __syncthreads();
  }

  // ---- scatter epilogue (r10-proven) ----
#pragma unroll
  for (int ni = 0; ni < 4; ++ni) {
    const int o = n0 + wc * 64 + ni * 16 + lo;
    const float bv = bias[o];
    const int h = o / 192, rem = o - h * 192, which = rem >> 6, d = rem & 63;
#pragma unroll
    for (int mi = 0; mi < 4; ++mi) {
      const int mb = m0 + wr * 64 + mi * 16 + lg * 4;
      const int bb = mb >> 11, t0 = mb & 2047;
      const int bh = bb * NH + h;
      if (which == 2) {
        u16x4 pk;
#pragma unroll
        for (int r = 0; r < 4; ++r) pk[r] = f2bf(acc[mi][ni][r] + bv);
        *(u16x4*)&VTb[((size_t)bh * DK + d) * TT + t0] = pk;
      } else if (which == 1) {
#pragma unroll
        for (int r = 0; r < 4; ++r)
          Kb[((size_t)bh * TT + t0 + r) * DK + d] = f2bf(acc[mi][ni][r] + bv);
      } else {
#pragma unroll
        for (int r = 0; r < 4; ++r)
          Qb[((size_t)bh * TT + t0 + r) * DK + d] = f2bf((acc[mi][ni][r] + bv) * QSC);
      }
    }
  }
}

// ---------------- Flash attention v10: no-max softmax, 4 blocks/CU ----------
__global__ void __launch_bounds__(256, 4)
attn10(const u16* __restrict__ Qb, const u16* __restrict__ Kb,
       const u16* __restrict__ VTb, u16* __restrict__ PA, u16* __restrict__ PB,
       float* __restrict__ ML) {
  __shared__ u16 Kls[2][64][64];
  __shared__ u16 Vls[2][64][64];
  const int tid = threadIdx.x, lane = tid & 63, wv = tid >> 6;
  const int lq = lane & 31, h = lane >> 5;
  const int id = blockIdx.x;
  const int w = (id & 7) * 128 + (id >> 3);  // logical work index, XCD-chunked
  const int bh = w >> 4;                     // 8 bh per XCD
  const int pj = w & 7;                      // pair index
  const int sp = (w >> 3) & 1;               // kv parity
  const int bb = bh >> 4, head = bh & 15;
  const u16* Qp = Qb + (size_t)bh * TT * DK;
  const u16* Kp = Kb + (size_t)bh * TT * DK;
  const u16* Vp = VTb + (size_t)bh * DK * TT;
  const int rin = lane >> 3, blk = lane & 7;
  u16* PO = sp ? PB : PA;

  const u16* kga = Kp + (size_t)(wv * 16 + rin) * DK + (blk ^ rin) * 8;
  const u16* vga = Vp + (size_t)(wv * 16 + rin) * TT + (blk ^ rin) * 8;
  u16* kls0 = &Kls[0][wv * 16][0];
  u16* vls0 = &Vls[0][wv * 16][0];
  const int lds_half = 64 * 64;  // u16 elems between buf 0 and 1

#define STAGE10(bufi, kvt_)                                                 \
  {                                                                         \
    const int o_ = (bufi) * lds_half;                                       \
    glds16(kga + (size_t)(kvt_) * 4096, kls0 + o_);                         \
    glds16(kga + (size_t)(kvt_) * 4096 + 512, kls0 + o_ + 512);             \
    glds16(vga + (size_t)(kvt_) * 64, vls0 + o_);                           \
    glds16(vga + (size_t)(kvt_) * 64 + 8 * TT, vls0 + o_ + 512);            \
  }

  for (int pi = 0; pi < 2; ++pi) {
    const int qtile = pi ? (15 - pj) : pj;
    const int q0w = qtile * 128 + wv * 32;
    const int qrow = q0w + lq;

    short8 qw[4];
#pragma unroll
    for (int kk = 0; kk < 4; ++kk)
      qw[kk] = *(const short8*)&Qp[(size_t)qrow * DK + kk * 16 + h * 8];

    f32x16 oa0, oa1;
#pragma unroll
    for (int r = 0; r < 16; ++r) { oa0[r] = 0.f; oa1[r] = 0.f; }
    float l_s = 0.f;

    const int nt = 2 * qtile + 2;
    STAGE10(0, sp);
    __syncthreads();
    int buf = 0;
    for (int kvt = sp; kvt < nt; kvt += 2) {
      const int kv0 = kvt * 64;
      if (kvt + 2 < nt) STAGE10(buf ^ 1, kvt + 2);
      if (kv0 <= q0w + 31) {
        f32x16 s0, s1;
#pragma unroll
        for (int r = 0; r < 16; ++r) { s0[r] = 0.f; s1[r] = 0.f; }
        __builtin_amdgcn_s_setprio(1);
#pragma unroll
        for (int kk = 0; kk < 4; ++kk) {
          const short8 kf0 = *(const short8*)&Kls[buf][lq][(((2 * kk + h) ^ (lq & 7)) * 8)];
          const short8 kf1 = *(const short8*)&Kls[buf][32 + lq][(((2 * kk + h) ^ (lq & 7)) * 8)];
          s0 = mfma32(kf0, qw[kk], s0);
          s1 = mfma32(kf1, qw[kk], s1);
        }
        __builtin_amdgcn_s_setprio(0);
        const bool diag = (kv0 + 63 > q0w);
        if (diag) {
          const int lim = qrow - kv0 - 4 * h;
#pragma unroll
          for (int r = 0; r < 16; ++r) {
            const int kl = (r & 3) + 8 * (r >> 2);
            s0[r] = (kl <= lim) ? s0[r] : -1e30f;
            s1[r] = (kl + 32 <= lim) ? s1[r] : -1e30f;
          }
        }
        float rsa = 0.f, rsb = 0.f, rsc = 0.f, rsd = 0.f;
#pragma unroll
        for (int r = 0; r < 16; r += 4) {
          const float a0 = fexp2(s0[r]),     a1 = fexp2(s1[r]);
          const float b0 = fexp2(s0[r + 1]), b1 = fexp2(s1[r + 1]);
          const float c0 = fexp2(s0[r + 2]), c1 = fexp2(s1[r + 2]);
          const float d0 = fexp2(s0[r + 3]), d1 = fexp2(s1[r + 3]);
          s0[r] = a0; s1[r] = a1; s0[r + 1] = b0; s1[r + 1] = b1;
          s0[r + 2] = c0; s1[r + 2] = c1; s0[r + 3] = d0; s1[r + 3] = d1;
          rsa += a0 + a1; rsb += b0 + b1; rsc += c0 + c1; rsd += d0 + d1;
        }
        float rs = (rsa + rsb) + (rsc + rsd);
        rs += __shfl_xor(rs, 32);
        l_s += rs;
#pragma unroll
        for (int s = 0; s < 2; ++s) {
          u32 C[8];
#pragma unroll
          for (int j = 0; j < 8; ++j)
            C[j] = s ? cvtpk(s1[2 * j], s1[2 * j + 1]) : cvtpk(s0[2 * j], s0[2 * j + 1]);
#pragma unroll
          for (int b = 0; b < 2; ++b) {
            const int o = 4 * b;
            const u32 D1 = h ? C[o + 0] : C[o + 2];
            const u32 D2 = h ? C[o + 1] : C[o + 3];
            const u32 R1 = __shfl_xor(D1, 32);
            const u32 R2 = __shfl_xor(D2, 32);
            union { u32x4 w; short8 s8; } pa;
            pa.w[0] = h ? R1 : C[o + 0];
            pa.w[1] = h ? R2 : C[o + 1];
            pa.w[2] = h ? C[o + 2] : R1;
            pa.w[3] = h ? C[o + 3] : R2;
            const int ks = 2 * s + b;
            const short8 vb0 = *(const short8*)&Vls[buf][lq][(((2 * ks + h) ^ (lq & 7)) * 8)];
            const short8 vb1 = *(const short8*)&Vls[buf][32 + lq][(((2 * ks + h) ^ (lq & 7)) * 8)];
            __builtin_amdgcn_s_setprio(1);
            oa0 = mfma32(pa.s8, vb0, oa0);
            oa1 = mfma32(pa.s8, vb1, oa1);
            __builtin_amdgcn_s_setprio(0);
          }
        }
      }
      __syncthreads();
      buf ^= 1;
    }

#pragma unroll
    for (int r = 0; r < 16; ++r) {
      const int t = q0w + (r & 3) + 8 * (r >> 2) + 4 * h;
      const size_t rowb = ((size_t)(bb * TT + t)) * CDIM + head * DK;
      PO[rowb + lq] = f2bf(oa0[r]);
      PO[rowb + 32 + lq] = f2bf(oa1[r]);
    }
    if (h == 0) ML[((size_t)(sp * 64 + bh) << 11) + qrow] = l_s;
    __syncthreads();
  }
#undef STAGE10
}

// ---------------- merge of the two kv-parity partials ----------------------
__global__ void attn_merge(const u16* PA, const u16* PB,
                           const float* __restrict__ ML, u16* Ctx) {
  const int row = blockIdx.x;  // b*2048 + t
  const int b = row >> 11, t = row & 2047;
  const int c = threadIdx.x * 4;
  const int head = c >> 6;
  const int bh = b * NH + head;
  const float lA = ML[((size_t)bh << 11) + t];
  const float lB = ML[((size_t)(64 + bh) << 11) + t];
  const float il = 1.0f / (lA + lB);
  const size_t idx = ((size_t)row) * CDIM + c;
  u16x4 pa = *(const u16x4*)&PA[idx];
  u16x4 pb = *(const u16x4*)&PB[idx];
  u16x4 o;
#pragma unroll
  for (int e = 0; e < 4; ++e) o[e] = f2bf((bf2f(pa[e]) + bf2f(pb[e])) * il);
  *(u16x4*)&Ctx[idx] = o;
}

// ---------------- Output GEMM v4: m97 structure + proven LDS swizzle --------
__global__ void out_gemm4(const u16* __restrict__ A, const u16* __restrict__ B,
                          const float* __restrict__ bias, float* __restrict__ Out) {
  __shared__ u16 As[128][64];
  __shared__ u16 Bs[128][64];
  const int tid = threadIdx.x, lane = tid & 63, wv = tid >> 6;
  const int wr = wv >> 1, wc = wv & 1, lo = lane & 15, lg = lane >> 4;
  const int m0 = blockIdx.x * 128, n0 = blockIdx.y * 128;
  const int rin = lane >> 3, blk = lane & 7;
  const int r7 = lo & 7;

  f32x4 acc[4][4];
  const f32x4 fz = {0.f, 0.f, 0.f, 0.f};
#pragma unroll
  for (int i = 0; i < 4; ++i)
#pragma unroll
    for (int j = 0; j < 4; ++j) acc[i][j] = fz;

  const u16* ga = A + (size_t)(m0 + 32 * wv + rin) * CDIM + (blk ^ rin) * 8;
  const u16* gb = B + (size_t)(n0 + 32 * wv + rin) * CDIM + (blk ^ rin) * 8;

  for (int k0 = 0; k0 < CDIM; k0 += 64) {
#pragma unroll
    for (int i = 0; i < 4; ++i) glds16(ga + k0 + (size_t)(8 * i) * CDIM, &As[32 * wv + 8 * i][0]);
#pragma unroll
    for (int i = 0; i < 4; ++i) glds16(gb + k0 + (size_t)(8 * i) * CDIM, &Bs[32 * wv + 8 * i][0]);
    __syncthreads();
#pragma unroll
    for (int kk = 0; kk < 2; ++kk) {
      short8 af[4], bf[4];
#pragma unroll
      for (int mi = 0; mi < 4; ++mi)
        af[mi] = *(const short8*)&As[wr * 64 + mi * 16 + lo][(((kk * 4 + lg) ^ r7) * 8)];
#pragma unroll
      for (int ni = 0; ni < 4; ++ni)
        bf[ni] = *(const short8*)&Bs[wc * 64 + ni * 16 + lo][(((kk * 4 + lg) ^ r7) * 8)];
#pragma unroll
      for (int mi = 0; mi < 4; ++mi)
#pragma unroll
        for (int ni = 0; ni < 4; ++ni)
          acc[mi][ni] = __builtin_amdgcn_mfma_f32_16x16x32_bf16(af[mi], bf[ni], acc[mi][ni], 0, 0, 0);
    }
    __syncthreads();
  }

#pragma unroll
  for (int ni = 0; ni < 4; ++ni) {
    const int o = n0 + wc * 64 + ni * 16 + lo;
    const float bv = bias[o];
#pragma unroll
    for (int mi = 0; mi < 4; ++mi)
#pragma unroll
      for (int r = 0; r < 4; ++r)
        Out[(size_t)(m0 + wr * 64 + mi * 16 + lg * 4 + r) * CDIM + o] = acc[mi][ni][r] + bv;
  }
}

extern "C" void kernel_launch(void* const* d_in, const int* in_sizes, int n_in,
                              void* d_out, int out_size, void* d_ws, size_t ws_size,
                              hipStream_t stream) {
  const float* X = (const float*)d_in[0];
  const float* Wqkv = (const float*)d_in[1];
  const float* bqkv = (const float*)d_in[2];
  const float* Wout = (const float*)d_in[3];
  const float* bout = (const float*)d_in[4];
  float* Out = (float*)d_out;

  u16* Xb  = (u16*)d_ws;              // 8,388,608 u16 (reused as PB after qkv)
  u16* W1b = Xb + 8388608;            // 3,145,728 u16 (reused as ML after qkv)
  u16* W2b = W1b + 3145728;           // 1,048,576
  u16* Qb  = W2b + 1048576;           // 8,388,608 (pre-scaled by QSC)
  u16* Kb  = Qb + 8388608;            // 8,388,608
  u16* VTb = Kb + 8388608;            // 8,388,608 (transposed: [bh][d][t])
  u16* Ctx = VTb + 8388608;           // 8,388,608 (PA partial, then merged in-place)

  conv_bf16b<<<1536, 256, 0, stream>>>(X, Wqkv, Wout, Xb, W1b, W2b);
  qkv_gemm9<<<dim3(64, 24), 256, 0, stream>>>(Xb, W1b, bqkv, Qb, Kb, VTb);
  attn10<<<dim3(1024), 256, 0, stream>>>(Qb, Kb, VTb, Ctx, Xb, (float*)W1b);
  attn_merge<<<8192, 256, 0, stream>>>(Ctx, Xb, (const float*)W1b, Ctx);
  out_gemm4<<<dim3(64, 8), 256, 0, stream>>>(Ctx, W2b, bout, Out);
}